// Round 1
// baseline (1085.167 us; speedup 1.0000x reference)
//
#include <hip/hip_runtime.h>
#include <hip/hip_bf16.h>

#define NUM_NODES 100000
#define EMBED_DIM 128
#define HIDDEN_DIM 512
#define NUM_EDGES 2000000
#define NUM_H 100000
#define LN_EPS 1e-5f

// ---------------- workspace layout (int units) ----------------
// counts  @ 0          (100000)
// cursor  @ 100096     (100000)
// offsets @ 200192     (100001)
// sorted  @ 300288     (2000000)
// total ints: 2300288  -> ~9.2 MB
#define OFF_COUNTS 0
#define OFF_CURSOR 100096
#define OFF_OFFSETS 200192
#define OFF_SORTED 300288

// ---------------- 1. histogram ----------------
__global__ __launch_bounds__(256) void hist_kernel(const int* __restrict__ eidx,
                                                   int* __restrict__ counts) {
    int e = blockIdx.x * 256 + threadIdx.x;
    if (e < NUM_EDGES) atomicAdd(&counts[eidx[e]], 1);
}

// ---------------- 2. exclusive scan over counts (single block) ----------------
__global__ __launch_bounds__(1024) void scan_kernel(const int* __restrict__ counts,
                                                    int* __restrict__ offsets) {
    __shared__ int wsum[16];
    __shared__ int woff[16];
    __shared__ int carry_s;
    const int tid = threadIdx.x;
    const int warp = tid >> 6, lane = tid & 63;
    if (tid == 0) carry_s = 0;
    __syncthreads();
    int total = 0;
    for (int base = 0; base < NUM_H; base += 1024) {
        int i = base + tid;
        int v = (i < NUM_H) ? counts[i] : 0;
        int incl = v;
        #pragma unroll
        for (int off = 1; off < 64; off <<= 1) {
            int t = __shfl(incl, lane - off);
            if (lane >= off) incl += t;
        }
        if (lane == 63) wsum[warp] = incl;
        __syncthreads();
        if (tid < 16) {
            int s = wsum[tid];
            int is = s;
            #pragma unroll
            for (int off = 1; off < 16; off <<= 1) {
                int t = __shfl(is, tid - off);
                if (tid >= off) is += t;
            }
            woff[tid] = carry_s + is - s;   // exclusive warp offset (incl. carry)
        }
        __syncthreads();
        if (i < NUM_H) offsets[i] = woff[warp] + incl - v;
        total = woff[15] + wsum[15];
        __syncthreads();
        if (tid == 0) carry_s = total;
    }
    if (tid == 0) offsets[NUM_H] = total;   // == NUM_EDGES
}

// ---------------- 3. scatter into CSR order ----------------
__global__ __launch_bounds__(256) void scatter_kernel(const int* __restrict__ nidx,
                                                      const int* __restrict__ eidx,
                                                      const int* __restrict__ offsets,
                                                      int* __restrict__ cursor,
                                                      int* __restrict__ sorted) {
    int e = blockIdx.x * 256 + threadIdx.x;
    if (e < NUM_EDGES) {
        int h = eidx[e];
        int pos = offsets[h] + atomicAdd(&cursor[h], 1);
        sorted[pos] = nidx[e];
    }
}

// ---------------- 4. fused aggregate + MLP ----------------
// Block = 256 threads (4 waves). Each block owns 16 hyperedges.
// Stage 0: each wave aggregates 4 hyperedges (mean+max) into LDS h-tile [16][256].
// Stage 1: f32 GEMM  z[16][512] = h @ W1 + b1  (acc in regs, z -> LDS).
// Stage 2: per-wave LayerNorm + ReLU + dot(W2) + b2 -> out.
__global__ __launch_bounds__(256) void fused_mlp_kernel(
        const float* __restrict__ embeds,
        const int* __restrict__ offsets,
        const int* __restrict__ sorted,
        const float* __restrict__ W1, const float* __restrict__ b1,
        const float* __restrict__ gamma, const float* __restrict__ beta,
        const float* __restrict__ W2, const float* __restrict__ b2,
        float* __restrict__ out) {
    __shared__ float zt[16][512];                       // 32 KB
    float (*ht)[256] = reinterpret_cast<float(*)[256]>(&zt[0][0]);  // first 16 KB

    const int tid  = threadIdx.x;
    const int warp = tid >> 6;
    const int lane = tid & 63;
    const int m0   = blockIdx.x * 16;

    // ---- stage 0: aggregation (mean | max) ----
    for (int rr = 0; rr < 4; ++rr) {
        const int row = warp * 4 + rr;        // 0..15
        const int h   = m0 + row;
        const int beg = offsets[h], end = offsets[h + 1];
        float2 sum = {0.f, 0.f};
        float2 mx  = {-3.402823466e38f, -3.402823466e38f};
        int node = (beg < end) ? sorted[beg] : 0;
        for (int i = beg; i < end; ++i) {
            int nn = (i + 1 < end) ? sorted[i + 1] : 0;   // prefetch next index
            const float2 v = *(const float2*)&embeds[node * EMBED_DIM + lane * 2];
            sum.x += v.x; sum.y += v.y;
            mx.x = fmaxf(mx.x, v.x); mx.y = fmaxf(mx.y, v.y);
            node = nn;
        }
        const int deg = end - beg;
        const float inv = deg ? 1.f / (float)deg : 0.f;
        if (!deg) { mx.x = 0.f; mx.y = 0.f; }
        float2 mean = {sum.x * inv, sum.y * inv};
        *(float2*)&ht[row][lane * 2]       = mean;
        *(float2*)&ht[row][128 + lane * 2] = mx;
    }
    __syncthreads();

    // ---- stage 1: GEMM z = h @ W1 + b1 ----
    // thread owns cols {2*tid, 2*tid+1}, all 16 rows
    float acc0[16], acc1[16];
    #pragma unroll
    for (int r = 0; r < 16; ++r) { acc0[r] = 0.f; acc1[r] = 0.f; }

    const int c0 = tid * 2;
    for (int k0 = 0; k0 < 256; k0 += 4) {
        float2 w[4];
        #pragma unroll
        for (int kk = 0; kk < 4; ++kk)
            w[kk] = *(const float2*)&W1[(k0 + kk) * HIDDEN_DIM + c0];
        #pragma unroll
        for (int r = 0; r < 16; ++r) {
            const float4 hv = *(const float4*)&ht[r][k0];   // wave-uniform broadcast
            acc0[r] += hv.x * w[0].x + hv.y * w[1].x + hv.z * w[2].x + hv.w * w[3].x;
            acc1[r] += hv.x * w[0].y + hv.y * w[1].y + hv.z * w[2].y + hv.w * w[3].y;
        }
    }
    const float2 bb = *(const float2*)&b1[c0];
    __syncthreads();      // done reading ht; safe to overwrite with z
    #pragma unroll
    for (int r = 0; r < 16; ++r) {
        float2 zv = {acc0[r] + bb.x, acc1[r] + bb.y};
        *(float2*)&zt[r][c0] = zv;
    }
    __syncthreads();

    // ---- stage 2: LayerNorm + ReLU + GEMV(W2) + b2 ----
    float g[8], bt[8], w2v[8];
    #pragma unroll
    for (int j = 0; j < 8; ++j) {
        g[j]   = gamma[lane + 64 * j];
        bt[j]  = beta[lane + 64 * j];
        w2v[j] = W2[lane + 64 * j];
    }
    const float b2v = b2[0];
    for (int rr = 0; rr < 4; ++rr) {
        const int r = warp * 4 + rr;
        float v[8];
        float s = 0.f;
        #pragma unroll
        for (int j = 0; j < 8; ++j) { v[j] = zt[r][lane + 64 * j]; s += v[j]; }
        #pragma unroll
        for (int off = 32; off; off >>= 1) s += __shfl_xor(s, off);
        const float mu = s * (1.f / 512.f);
        float q = 0.f;
        #pragma unroll
        for (int j = 0; j < 8; ++j) { const float d = v[j] - mu; q += d * d; }
        #pragma unroll
        for (int off = 32; off; off >>= 1) q += __shfl_xor(q, off);
        const float rs = rsqrtf(q * (1.f / 512.f) + LN_EPS);
        float dot = 0.f;
        #pragma unroll
        for (int j = 0; j < 8; ++j) {
            float y = (v[j] - mu) * rs * g[j] + bt[j];
            y = fmaxf(y, 0.f);
            dot += y * w2v[j];
        }
        #pragma unroll
        for (int off = 32; off; off >>= 1) dot += __shfl_xor(dot, off);
        if (lane == 0) out[m0 + r] = dot + b2v;
    }
}

extern "C" void kernel_launch(void* const* d_in, const int* in_sizes, int n_in,
                              void* d_out, int out_size, void* d_ws, size_t ws_size,
                              hipStream_t stream) {
    const float* embeds = (const float*)d_in[0];
    const int*   hidx   = (const int*)d_in[1];      // [2][E]
    const float* W1     = (const float*)d_in[2];
    const float* b1     = (const float*)d_in[3];
    const float* gamma  = (const float*)d_in[4];
    const float* beta   = (const float*)d_in[5];
    const float* W2     = (const float*)d_in[6];
    const float* b2     = (const float*)d_in[7];
    float*       out    = (float*)d_out;

    int* ws      = (int*)d_ws;
    int* counts  = ws + OFF_COUNTS;
    int* cursor  = ws + OFF_CURSOR;
    int* offsets = ws + OFF_OFFSETS;
    int* sorted  = ws + OFF_SORTED;

    const int* nidx = hidx;
    const int* eidx = hidx + NUM_EDGES;

    // zero counts + cursor (ws is poisoned to 0xAA before every launch)
    hipMemsetAsync(d_ws, 0, (size_t)OFF_OFFSETS * sizeof(int), stream);

    const int eb = (NUM_EDGES + 255) / 256;
    hist_kernel<<<eb, 256, 0, stream>>>(eidx, counts);
    scan_kernel<<<1, 1024, 0, stream>>>(counts, offsets);
    scatter_kernel<<<eb, 256, 0, stream>>>(nidx, eidx, offsets, cursor, sorted);
    fused_mlp_kernel<<<NUM_H / 16, 256, 0, stream>>>(embeds, offsets, sorted,
                                                     W1, b1, gamma, beta, W2, b2, out);
}

// Round 3
// 613.393 us; speedup vs baseline: 1.7691x; 1.7691x over previous
//
#include <hip/hip_runtime.h>
#include <hip/hip_bf16.h>

#define NUM_NODES 100000
#define EMBED_DIM 128
#define HIDDEN_DIM 512
#define NUM_EDGES 2000000
#define NUM_H 100000
#define LN_EPS 1e-5f
#define NCHUNK 98   // ceil(100000/1024)

// ---------------- workspace layout (int units) ----------------
#define OFF_COUNTS   0
#define OFF_CURSOR   100096
#define OFF_OFFSETS  200192
#define OFF_SORTED   300288
#define OFF_PARTIALS 2300288
#define OFF_BASES    2300416
#define OFF_W1HI     2300544   // 131072 bf16 = 65536 ints (256 KB)
#define OFF_W1LO     2366080   // contiguous after HI
// total: 2431616 ints ~ 9.3 MB

typedef __attribute__((ext_vector_type(8))) short bf16x8;
typedef __attribute__((ext_vector_type(4))) float f32x4;

__device__ __forceinline__ unsigned short f2bf(float x) {
    unsigned u = __float_as_uint(x);
    u += 0x7fff + ((u >> 16) & 1);          // RNE
    return (unsigned short)(u >> 16);
}
__device__ __forceinline__ float bf2f(unsigned short h) {
    return __uint_as_float(((unsigned)h) << 16);
}

// ---------------- 0. pack W1 into MFMA B-fragment order, split hi/lo ----------------
// elem index e = (t*512 + n)*32 + g*8 + j ; value = W1[t*32 + g*8 + j][n]
__global__ __launch_bounds__(256) void pack_w1(const float* __restrict__ W1,
                                               unsigned short* __restrict__ hi,
                                               unsigned short* __restrict__ lo) {
    int e = blockIdx.x * 256 + threadIdx.x;           // 131072 total
    int t = e >> 14, rem = e & 16383;
    int n = rem >> 5, gj = rem & 31;
    int k = t * 32 + gj;
    float x = W1[k * HIDDEN_DIM + n];
    unsigned short h = f2bf(x);
    hi[e] = h;
    lo[e] = f2bf(x - bf2f(h));
}

// ---------------- 1. histogram ----------------
__global__ __launch_bounds__(256) void hist_kernel(const int* __restrict__ eidx,
                                                   int* __restrict__ counts) {
    int e = blockIdx.x * 256 + threadIdx.x;
    if (e < NUM_EDGES) atomicAdd(&counts[eidx[e]], 1);
}

// ---------------- 2a. per-chunk local exclusive scan ----------------
__global__ __launch_bounds__(1024) void scan_partial(const int* __restrict__ counts,
                                                     int* __restrict__ offsets,
                                                     int* __restrict__ partials) {
    __shared__ int wsum[16];
    __shared__ int woff[16];
    const int tid = threadIdx.x, b = blockIdx.x;
    const int warp = tid >> 6, lane = tid & 63;
    const int i = b * 1024 + tid;
    int v = (i < NUM_H) ? counts[i] : 0;
    int incl = v;
    #pragma unroll
    for (int off = 1; off < 64; off <<= 1) {
        int t = __shfl(incl, lane - off);
        if (lane >= off) incl += t;
    }
    if (lane == 63) wsum[warp] = incl;
    __syncthreads();
    if (tid < 16) {
        int s = wsum[tid], is = s;
        #pragma unroll
        for (int off = 1; off < 16; off <<= 1) {
            int t = __shfl(is, tid - off);
            if (tid >= off) is += t;
        }
        woff[tid] = is - s;
    }
    __syncthreads();
    if (i < NUM_H) offsets[i] = woff[warp] + incl - v;
    if (tid == 0) partials[b] = woff[15] + wsum[15];
}

// ---------------- 2b. scan the 98 chunk totals ----------------
__global__ __launch_bounds__(128) void scan_base(const int* __restrict__ partials,
                                                 int* __restrict__ bases) {
    __shared__ int t0;
    const int tid = threadIdx.x;
    const int lane = tid & 63, w = tid >> 6;
    int v = (tid < NCHUNK) ? partials[tid] : 0;
    int incl = v;
    #pragma unroll
    for (int off = 1; off < 64; off <<= 1) {
        int t = __shfl(incl, lane - off);
        if (lane >= off) incl += t;
    }
    if (tid == 63) t0 = incl;
    __syncthreads();
    bases[tid] = incl - v + (w ? t0 : 0);
}

// ---------------- 2c. add chunk base ----------------
__global__ __launch_bounds__(1024) void scan_add(int* __restrict__ offsets,
                                                 const int* __restrict__ bases) {
    const int i = blockIdx.x * 1024 + threadIdx.x;
    if (i < NUM_H) offsets[i] += bases[blockIdx.x];
    if (i == 0) offsets[NUM_H] = NUM_EDGES;
}

// ---------------- 3. scatter into CSR order ----------------
__global__ __launch_bounds__(256) void scatter_kernel(const int* __restrict__ nidx,
                                                      const int* __restrict__ eidx,
                                                      const int* __restrict__ offsets,
                                                      int* __restrict__ cursor,
                                                      int* __restrict__ sorted) {
    int e = blockIdx.x * 256 + threadIdx.x;
    if (e < NUM_EDGES) {
        int h = eidx[e];
        int pos = offsets[h] + atomicAdd(&cursor[h], 1);
        sorted[pos] = nidx[e];
    }
}

// ---------------- 4. fused aggregate + MFMA MLP ----------------
// Block = 256 threads (4 waves), 16 hyperedges/block.
// Stage 0: each wave aggregates 4 rows (4-deep ILP), writes bf16 hi/lo A-tile
//          directly into XOR-swizzled LDS.
// Stage 1: 3-pass split-bf16 MFMA GEMM (16x16x32), B from pre-packed global.
// Stage 2: in-register LayerNorm + ReLU + GEMV via Σz/Σz² + tiny LDS reductions.
__global__ __launch_bounds__(256) void fused_mlp_kernel(
        const float* __restrict__ embeds,
        const int* __restrict__ offsets,
        const int* __restrict__ sorted,
        const char* __restrict__ w1pack,   // hi @0, lo @+262144
        const float* __restrict__ b1,
        const float* __restrict__ gamma, const float* __restrict__ beta,
        const float* __restrict__ W2, const float* __restrict__ b2,
        float* __restrict__ out) {
    __shared__ __align__(16) char A_hi[8192];   // [16 rows][256 cols] bf16, XOR-swizzled
    __shared__ __align__(16) char A_lo[8192];
    __shared__ float red_s[4][16];
    __shared__ float red_q[4][16];
    __shared__ float red_d[4][16];

    const int tid  = threadIdx.x;
    const int warp = tid >> 6;
    const int lane = tid & 63;
    const int m0   = blockIdx.x * 16;

    // ---- stage 0: aggregation (mean | max), lane covers dims {2l, 2l+1} ----
    for (int rr = 0; rr < 4; ++rr) {
        const int row = warp * 4 + rr;
        const int hh  = m0 + row;
        const int beg = offsets[hh], end = offsets[hh + 1];
        float2 s0 = {0.f, 0.f}, s1 = {0.f, 0.f}, s2 = {0.f, 0.f}, s3 = {0.f, 0.f};
        float2 x0 = {-3.4e38f, -3.4e38f}, x1 = x0, x2 = x0, x3 = x0;
        int i = beg;
        for (; i + 4 <= end; i += 4) {
            int n0 = sorted[i], n1 = sorted[i + 1], n2 = sorted[i + 2], n3 = sorted[i + 3];
            float2 v0 = *(const float2*)&embeds[(size_t)n0 * EMBED_DIM + lane * 2];
            float2 v1 = *(const float2*)&embeds[(size_t)n1 * EMBED_DIM + lane * 2];
            float2 v2 = *(const float2*)&embeds[(size_t)n2 * EMBED_DIM + lane * 2];
            float2 v3 = *(const float2*)&embeds[(size_t)n3 * EMBED_DIM + lane * 2];
            s0.x += v0.x; s0.y += v0.y; x0.x = fmaxf(x0.x, v0.x); x0.y = fmaxf(x0.y, v0.y);
            s1.x += v1.x; s1.y += v1.y; x1.x = fmaxf(x1.x, v1.x); x1.y = fmaxf(x1.y, v1.y);
            s2.x += v2.x; s2.y += v2.y; x2.x = fmaxf(x2.x, v2.x); x2.y = fmaxf(x2.y, v2.y);
            s3.x += v3.x; s3.y += v3.y; x3.x = fmaxf(x3.x, v3.x); x3.y = fmaxf(x3.y, v3.y);
        }
        for (; i < end; ++i) {
            int n0 = sorted[i];
            float2 v0 = *(const float2*)&embeds[(size_t)n0 * EMBED_DIM + lane * 2];
            s0.x += v0.x; s0.y += v0.y; x0.x = fmaxf(x0.x, v0.x); x0.y = fmaxf(x0.y, v0.y);
        }
        const int deg = end - beg;
        const float inv = deg ? 1.f / (float)deg : 0.f;
        float2 mean = {(s0.x + s1.x + s2.x + s3.x) * inv, (s0.y + s1.y + s2.y + s3.y) * inv};
        float2 mx   = {fmaxf(fmaxf(x0.x, x1.x), fmaxf(x2.x, x3.x)),
                       fmaxf(fmaxf(x0.y, x1.y), fmaxf(x2.y, x3.y))};
        if (!deg) { mx.x = 0.f; mx.y = 0.f; }
        const unsigned swz = ((unsigned)(row & 7)) << 4;
        const unsigned bm  = ((unsigned)(row * 512 + lane * 4)) ^ swz;        // cols 2l,2l+1
        const unsigned bx  = ((unsigned)(row * 512 + 256 + lane * 4)) ^ swz;  // cols 128+2l
        unsigned short h0 = f2bf(mean.x), h1 = f2bf(mean.y);
        *(unsigned*)(A_hi + bm) = (unsigned)h0 | ((unsigned)h1 << 16);
        *(unsigned*)(A_lo + bm) = (unsigned)f2bf(mean.x - bf2f(h0)) |
                                  ((unsigned)f2bf(mean.y - bf2f(h1)) << 16);
        unsigned short g0 = f2bf(mx.x), g1 = f2bf(mx.y);
        *(unsigned*)(A_hi + bx) = (unsigned)g0 | ((unsigned)g1 << 16);
        *(unsigned*)(A_lo + bx) = (unsigned)f2bf(mx.x - bf2f(g0)) |
                                  ((unsigned)f2bf(mx.y - bf2f(g1)) << 16);
    }
    __syncthreads();

    // ---- stage 1: z = h @ W1  (3-pass split-bf16 MFMA 16x16x32) ----
    const int c = lane & 15, g = lane >> 4;
    const int wbase = warp * 128;              // this wave's 128-col slice
    f32x4 acc[8];
    #pragma unroll
    for (int nt = 0; nt < 8; ++nt) acc[nt] = (f32x4){0.f, 0.f, 0.f, 0.f};

    const char* bptr = w1pack + (size_t)((wbase + c) * 64 + g * 16);
    const unsigned swzA = ((unsigned)(c & 7)) << 4;
    #pragma unroll
    for (int t = 0; t < 8; ++t) {
        const unsigned ab = ((unsigned)(c * 512 + t * 64 + g * 16)) ^ swzA;
        bf16x8 ahi = *(const bf16x8*)(A_hi + ab);
        bf16x8 alo = *(const bf16x8*)(A_lo + ab);
        #pragma unroll
        for (int nt = 0; nt < 8; ++nt) {
            const char* p = bptr + t * 32768 + nt * 1024;
            bf16x8 bhi = *(const bf16x8*)p;
            bf16x8 blo = *(const bf16x8*)(p + 262144);
            acc[nt] = __builtin_amdgcn_mfma_f32_16x16x32_bf16(ahi, bhi, acc[nt], 0, 0, 0);
            acc[nt] = __builtin_amdgcn_mfma_f32_16x16x32_bf16(alo, bhi, acc[nt], 0, 0, 0);
            acc[nt] = __builtin_amdgcn_mfma_f32_16x16x32_bf16(ahi, blo, acc[nt], 0, 0, 0);
        }
    }

    // ---- stage 2: bias + LayerNorm + ReLU + GEMV, in-register ----
    // lane holds z[row = 4g+q][col = wbase + nt*16 + c]
    float b1v[8], gv[8], bev[8], w2v[8];
    #pragma unroll
    for (int nt = 0; nt < 8; ++nt) {
        const int col = wbase + nt * 16 + c;
        b1v[nt] = b1[col]; gv[nt] = gamma[col]; bev[nt] = beta[col]; w2v[nt] = W2[col];
    }
    float zv[8][4];
    float s[4], sq[4];
    #pragma unroll
    for (int q = 0; q < 4; ++q) { s[q] = 0.f; sq[q] = 0.f; }
    #pragma unroll
    for (int nt = 0; nt < 8; ++nt)
        #pragma unroll
        for (int q = 0; q < 4; ++q) {
            float z = acc[nt][q] + b1v[nt];
            zv[nt][q] = z;
            s[q] += z; sq[q] += z * z;
        }
    #pragma unroll
    for (int q = 0; q < 4; ++q)
        #pragma unroll
        for (int off = 1; off < 16; off <<= 1) {
            s[q]  += __shfl_xor(s[q],  off);
            sq[q] += __shfl_xor(sq[q], off);
        }
    if (c == 0)
        #pragma unroll
        for (int q = 0; q < 4; ++q) {
            red_s[warp][g * 4 + q] = s[q];
            red_q[warp][g * 4 + q] = sq[q];
        }
    __syncthreads();
    float d[4];
    #pragma unroll
    for (int q = 0; q < 4; ++q) {
        const int row = g * 4 + q;
        float S = red_s[0][row] + red_s[1][row] + red_s[2][row] + red_s[3][row];
        float Q = red_q[0][row] + red_q[1][row] + red_q[2][row] + red_q[3][row];
        float mu = S * (1.f / 512.f);
        float var = Q * (1.f / 512.f) - mu * mu;
        float rs = rsqrtf(var + LN_EPS);
        float acc_d = 0.f;
        #pragma unroll
        for (int nt = 0; nt < 8; ++nt) {
            float y = (zv[nt][q] - mu) * rs * gv[nt] + bev[nt];
            y = fmaxf(y, 0.f);
            acc_d += y * w2v[nt];
        }
        d[q] = acc_d;
    }
    #pragma unroll
    for (int q = 0; q < 4; ++q)
        #pragma unroll
        for (int off = 1; off < 16; off <<= 1) d[q] += __shfl_xor(d[q], off);
    if (c == 0)
        #pragma unroll
        for (int q = 0; q < 4; ++q) red_d[warp][g * 4 + q] = d[q];
    __syncthreads();
    if (tid < 16)
        out[m0 + tid] = red_d[0][tid] + red_d[1][tid] + red_d[2][tid] + red_d[3][tid] + b2[0];
}

extern "C" void kernel_launch(void* const* d_in, const int* in_sizes, int n_in,
                              void* d_out, int out_size, void* d_ws, size_t ws_size,
                              hipStream_t stream) {
    const float* embeds = (const float*)d_in[0];
    const int*   hidx   = (const int*)d_in[1];
    const float* W1     = (const float*)d_in[2];
    const float* b1     = (const float*)d_in[3];
    const float* gamma  = (const float*)d_in[4];
    const float* beta   = (const float*)d_in[5];
    const float* W2     = (const float*)d_in[6];
    const float* b2     = (const float*)d_in[7];
    float*       out    = (float*)d_out;

    int* ws       = (int*)d_ws;
    int* counts   = ws + OFF_COUNTS;
    int* cursor   = ws + OFF_CURSOR;
    int* offsets  = ws + OFF_OFFSETS;
    int* sorted   = ws + OFF_SORTED;
    int* partials = ws + OFF_PARTIALS;
    int* bases    = ws + OFF_BASES;
    unsigned short* w1hi = (unsigned short*)(ws + OFF_W1HI);
    unsigned short* w1lo = (unsigned short*)(ws + OFF_W1LO);

    const int* nidx = hidx;
    const int* eidx = hidx + NUM_EDGES;

    hipMemsetAsync(d_ws, 0, (size_t)OFF_OFFSETS * sizeof(int), stream);

    pack_w1<<<512, 256, 0, stream>>>(W1, w1hi, w1lo);
    const int eb = (NUM_EDGES + 255) / 256;
    hist_kernel<<<eb, 256, 0, stream>>>(eidx, counts);
    scan_partial<<<NCHUNK, 1024, 0, stream>>>(counts, offsets, partials);
    scan_base<<<1, 128, 0, stream>>>(partials, bases);
    scan_add<<<NCHUNK, 1024, 0, stream>>>(offsets, bases);
    scatter_kernel<<<eb, 256, 0, stream>>>(nidx, eidx, offsets, cursor, sorted);
    fused_mlp_kernel<<<NUM_H / 16, 256, 0, stream>>>(embeds, offsets, sorted,
                                                     (const char*)(ws + OFF_W1HI),
                                                     b1, gamma, beta, W2, b2, out);
}